// Round 2
// baseline (445.350 us; speedup 1.0000x reference)
//
#include <hip/hip_runtime.h>

#define BSZ 64
#define SEQ 512
#define HID 768
#define NK  21

// ---------------- GEMM + bias: logits = hidden @ W + b ----------------
// Thread-per-row: W accessed at wave-uniform addresses (scalar-load path /
// L1 broadcast), 21 fp32 accumulators, float4 hidden loads. No LDS.
__global__ __launch_bounds__(64) void gemm_bias_kernel(
    const float* __restrict__ hidden, const float* __restrict__ W,
    const float* __restrict__ bias, float* __restrict__ out)
{
    const int r = blockIdx.x * 64 + threadIdx.x;          // 0 .. 32767
    const float4* hp = (const float4*)(hidden + (size_t)r * HID);

    float acc[NK];
    #pragma unroll
    for (int k = 0; k < NK; ++k) acc[k] = 0.f;

    #pragma unroll 2
    for (int j4 = 0; j4 < HID / 4; ++j4) {                // 192 iterations
        const float4 h = hp[j4];
        const float* w0 = W + (size_t)(4 * j4) * NK;      // wave-uniform
        #pragma unroll
        for (int k = 0; k < NK; ++k) {
            float a = acc[k];
            a = fmaf(h.x, w0[k           ], a);
            a = fmaf(h.y, w0[NK     + k  ], a);
            a = fmaf(h.z, w0[2 * NK + k  ], a);
            a = fmaf(h.w, w0[3 * NK + k  ], a);
            acc[k] = a;
        }
    }

    float* op = out + (size_t)r * NK;
    #pragma unroll
    for (int k = 0; k < NK; ++k) op[k] = acc[k] + bias[k];
}

// ---------------- CRF: one wave per batch, linear-space scan ----------------
__global__ __launch_bounds__(64) void crf_kernel(
    const float* __restrict__ logits,
    const float* __restrict__ start_t,
    const float* __restrict__ trans,
    const float* __restrict__ end_t,
    const int* __restrict__ labels,
    const int* __restrict__ mask,
    float* __restrict__ per_batch)
{
    __shared__ __align__(16) float Xl[SEQ * NK];  // raw logits, then exp(lg - C[t])
    __shared__ float C[SEQ];                      // C[t] = lg[t][0]
    __shared__ __align__(16) float avec[24];      // linear alpha, padded to 24

    const int b    = blockIdx.x;
    const int lane = threadIdx.x;                 // block = exactly 1 wave

    // ---- stage raw logits (coalesced float4) ----
    {
        const float4* g4 = (const float4*)(logits + (size_t)b * SEQ * NK);
        float4* l4 = (float4*)Xl;
        for (int idx = lane; idx < SEQ * NK / 4; idx += 64) l4[idx] = g4[idx];
    }

    const int* lab = labels + b * SEQ;
    const int* msk = mask   + b * SEQ;

    // ---- sequence length (mask is a prefix of ones) ----
    int cnt = 0;
    for (int t = lane; t < SEQ; t += 64) cnt += (msk[t] != 0);
    #pragma unroll
    for (int off = 32; off > 0; off >>= 1) cnt += __shfl_xor(cnt, off, 64);
    const int L = cnt;

    __syncthreads();  // raw logits staged

    // ---- numerator (gold-path score), wave-parallel over t (raw logits) ----
    float numacc = 0.f;
    for (int t = lane; t < L; t += 64) {
        if (t == 0) numacc += start_t[lab[0]] + Xl[lab[0]];
        else        numacc += Xl[t * NK + lab[t]] + trans[lab[t - 1] * NK + lab[t]];
    }
    if (lane == 0) numacc += end_t[lab[L - 1]];
    #pragma unroll
    for (int off = 32; off > 0; off >>= 1) numacc += __shfl_xor(numacc, off, 64);
    const float num = numacc;

    // ---- extract per-step offsets C[t] = lg[t][0] ----
    for (int t = lane; t < SEQ; t += 64) C[t] = Xl[t * NK];
    __syncthreads();

    // ---- transform in place: Xl[t][j] = exp(lg[t][j] - C[t]) ----
    for (int idx = lane; idx < SEQ * NK; idx += 64) {
        const int t = idx / 21;
        Xl[idx] = __expf(Xl[idx] - C[t]);
    }
    if (lane < 3) avec[21 + lane] = 0.f;          // pad lanes (never rewritten)
    __syncthreads();

    // ---- per-lane constants ----
    const int jj = (lane < NK) ? lane : NK - 1;   // dup lanes >= 21 onto j=20
    float Ecol[24];
    #pragma unroll
    for (int k = 0; k < NK; ++k) Ecol[k] = __expf(trans[k * NK + jj]);
    Ecol[21] = Ecol[22] = Ecol[23] = 0.f;
    const float Eend = __expf(end_t[jj]);

    // ---- init: a_j = exp(start_j + lg0_j - C[0]), O = C[0] (folded into Csum) ----
    float a = __expf(start_t[jj]) * Xl[jj];
    float Orenorm = 0.f;
    avec[jj] = a;                                 // dup lanes write identical value

    const float4* A4 = (const float4*)avec;

    // ---- linear-space forward scan ----
    for (int t = 1; t < L; ++t) {
        const float x = Xl[t * NK + jj];          // independent of avec chain
        float4 v0 = A4[0], v1 = A4[1], v2 = A4[2], v3 = A4[3], v4 = A4[4], v5 = A4[5];
        float s0 = 0.f, s1 = 0.f, s2 = 0.f;
        s0 = fmaf(v0.x, Ecol[ 0], s0); s1 = fmaf(v0.y, Ecol[ 1], s1); s2 = fmaf(v0.z, Ecol[ 2], s2);
        s0 = fmaf(v0.w, Ecol[ 3], s0); s1 = fmaf(v1.x, Ecol[ 4], s1); s2 = fmaf(v1.y, Ecol[ 5], s2);
        s0 = fmaf(v1.z, Ecol[ 6], s0); s1 = fmaf(v1.w, Ecol[ 7], s1); s2 = fmaf(v2.x, Ecol[ 8], s2);
        s0 = fmaf(v2.y, Ecol[ 9], s0); s1 = fmaf(v2.z, Ecol[10], s1); s2 = fmaf(v2.w, Ecol[11], s2);
        s0 = fmaf(v3.x, Ecol[12], s0); s1 = fmaf(v3.y, Ecol[13], s1); s2 = fmaf(v3.z, Ecol[14], s2);
        s0 = fmaf(v3.w, Ecol[15], s0); s1 = fmaf(v4.x, Ecol[16], s1); s2 = fmaf(v4.y, Ecol[17], s2);
        s0 = fmaf(v4.z, Ecol[18], s0); s1 = fmaf(v4.w, Ecol[19], s1); s2 = fmaf(v5.x, Ecol[20], s2);

        a = ((s0 + s1) + s2) * x;

        if ((t & 3) == 0) {                       // renorm by lane-0 value (exact algebra)
            const float m = __uint_as_float(
                __builtin_amdgcn_readfirstlane(__float_as_uint(a)));
            a *= 1.0f / m;
            Orenorm += __logf(m);
        }
        avec[jj] = a;                             // DS in-order per wave: next iter sees it
    }

    // ---- offset sum: Csum = sum_{t<L} C[t] ----
    float cs = 0.f;
    for (int t = lane; t < L; t += 64) cs += C[t];
    #pragma unroll
    for (int off = 32; off > 0; off >>= 1) cs += __shfl_xor(cs, off, 64);

    // ---- logZ = Csum + Orenorm + log(sum_j a_j * exp(end_j)) ----
    float val = (lane < NK) ? a * Eend : 0.f;
    #pragma unroll
    for (int off = 32; off > 0; off >>= 1) val += __shfl_xor(val, off, 64);

    if (lane == 0) per_batch[b] = cs + Orenorm + __logf(val) - num;
}

// ---------------- final reduce: nll = sum_b (logZ_b - num_b) ----------------
__global__ __launch_bounds__(64) void reduce_kernel(
    const float* __restrict__ pb, float* __restrict__ out)
{
    float v = pb[threadIdx.x];
    #pragma unroll
    for (int off = 32; off > 0; off >>= 1) v += __shfl_xor(v, off, 64);
    if (threadIdx.x == 0) out[BSZ * SEQ * NK] = v;
}

extern "C" void kernel_launch(void* const* d_in, const int* in_sizes, int n_in,
                              void* d_out, int out_size, void* d_ws, size_t ws_size,
                              hipStream_t stream)
{
    const float* hidden  = (const float*)d_in[0];
    const float* W       = (const float*)d_in[1];
    const float* bias    = (const float*)d_in[2];
    const float* start_t = (const float*)d_in[3];
    const float* trans   = (const float*)d_in[4];
    const float* end_t   = (const float*)d_in[5];
    const int*   labels  = (const int*)d_in[6];
    const int*   mask    = (const int*)d_in[7];
    float* out = (float*)d_out;
    float* pb  = (float*)d_ws;

    gemm_bias_kernel<<<(BSZ * SEQ) / 64, 64, 0, stream>>>(hidden, W, bias, out);
    crf_kernel<<<BSZ, 64, 0, stream>>>(out, start_t, trans, end_t, labels, mask, pb);
    reduce_kernel<<<1, 64, 0, stream>>>(pb, out);
}

// Round 3
// 304.418 us; speedup vs baseline: 1.4630x; 1.4630x over previous
//
#include <hip/hip_runtime.h>

#define BSZ 64
#define SEQ 512
#define HID 768
#define NK  21

#define REP21(X) X(0) X(1) X(2) X(3) X(4) X(5) X(6) X(7) X(8) X(9) X(10) \
                 X(11) X(12) X(13) X(14) X(15) X(16) X(17) X(18) X(19) X(20)

// ---------------- GEMM + bias: logits = hidden @ W + b ----------------
// Block = 4 waves, 64 rows. Wave p covers hidden cols [p*192,(p+1)*192);
// lane = row. W addresses are wave-uniform (p via readfirstlane) -> scalar
// loads; hidden via float4; partials combined through LDS; coalesced stores.
__global__ __launch_bounds__(256) void gemm_bias_kernel(
    const float* __restrict__ hidden, const float* __restrict__ W,
    const float* __restrict__ bias, float* __restrict__ out)
{
    __shared__ float part[4][64 * NK];                    // 21.5 KB

    const int lane = threadIdx.x & 63;
    const int p    = __builtin_amdgcn_readfirstlane(threadIdx.x >> 6);
    const int r    = blockIdx.x * 64 + lane;

    const float4* hp = (const float4*)(hidden + (size_t)r * HID + p * (HID / 4));
    const float*  wb = W + (size_t)p * (HID / 4) * NK;

#define DECL(i) float a##i = 0.f;
    REP21(DECL)
#undef DECL

    #pragma unroll 4
    for (int j = 0; j < HID / 16; ++j) {                  // 48 float4 loads
        const float4 h = hp[j];
        const float* w = wb + j * (4 * NK);               // wave-uniform addr
#define STEP(i) a##i = fmaf(h.w, w[63 + i], fmaf(h.z, w[42 + i], \
                      fmaf(h.y, w[21 + i], fmaf(h.x, w[i], a##i))));
        REP21(STEP)
#undef STEP
    }

    float* pp = &part[p][lane * NK];
#define ST(i) pp[i] = a##i;
    REP21(ST)
#undef ST
    __syncthreads();

    const int base_out = blockIdx.x * (64 * NK);
    for (int idx = threadIdx.x; idx < 64 * NK; idx += 256) {
        const int k = idx - (idx / NK) * NK;
        const float s = part[0][idx] + part[1][idx] + part[2][idx] + part[3][idx];
        out[base_out + idx] = s + bias[k];
    }
}

// ---------------- CRF: one wave per batch, linear-space scan ----------------
__global__ __launch_bounds__(64) void crf_kernel(
    const float* __restrict__ logits,
    const float* __restrict__ start_t,
    const float* __restrict__ trans,
    const float* __restrict__ end_t,
    const int* __restrict__ labels,
    const int* __restrict__ mask,
    float* __restrict__ per_batch)
{
    __shared__ __align__(16) float Xl[SEQ * NK];  // raw logits, then exp(lg - C[t])
    __shared__ float C[SEQ];                      // C[t] = lg[t][0]
    __shared__ __align__(16) float avec[24];      // linear alpha, padded to 24

    const int b    = blockIdx.x;
    const int lane = threadIdx.x;                 // block = exactly 1 wave

    // ---- stage raw logits (coalesced float4) ----
    {
        const float4* g4 = (const float4*)(logits + (size_t)b * SEQ * NK);
        float4* l4 = (float4*)Xl;
        for (int idx = lane; idx < SEQ * NK / 4; idx += 64) l4[idx] = g4[idx];
    }

    const int* lab = labels + b * SEQ;
    const int* msk = mask   + b * SEQ;

    // ---- sequence length (mask is a prefix of ones) ----
    int cnt = 0;
    for (int t = lane; t < SEQ; t += 64) cnt += (msk[t] != 0);
    #pragma unroll
    for (int off = 32; off > 0; off >>= 1) cnt += __shfl_xor(cnt, off, 64);
    const int L = cnt;

    __syncthreads();  // raw logits staged

    // ---- numerator (gold-path score), wave-parallel over t (raw logits) ----
    float numacc = 0.f;
    for (int t = lane; t < L; t += 64) {
        if (t == 0) numacc += start_t[lab[0]] + Xl[lab[0]];
        else        numacc += Xl[t * NK + lab[t]] + trans[lab[t - 1] * NK + lab[t]];
    }
    if (lane == 0) numacc += end_t[lab[L - 1]];
    #pragma unroll
    for (int off = 32; off > 0; off >>= 1) numacc += __shfl_xor(numacc, off, 64);
    const float num = numacc;

    // ---- extract per-step offsets C[t] = lg[t][0] ----
    for (int t = lane; t < SEQ; t += 64) C[t] = Xl[t * NK];
    __syncthreads();

    // ---- transform in place: Xl[t][j] = exp(lg[t][j] - C[t]) ----
    for (int idx = lane; idx < SEQ * NK; idx += 64) {
        const int t = idx / 21;
        Xl[idx] = __expf(Xl[idx] - C[t]);
    }
    if (lane < 3) avec[21 + lane] = 0.f;          // pad lanes (never rewritten)
    __syncthreads();

    // ---- per-lane constants ----
    const int jj = (lane < NK) ? lane : NK - 1;   // dup lanes >= 21 onto j=20
    float Ecol[24];
    #pragma unroll
    for (int k = 0; k < NK; ++k) Ecol[k] = __expf(trans[k * NK + jj]);
    Ecol[21] = Ecol[22] = Ecol[23] = 0.f;
    const float Eend = __expf(end_t[jj]);

    // ---- init: a_j = exp(start_j + lg0_j - C[0]) ----
    float a = __expf(start_t[jj]) * Xl[jj];
    float Orenorm = 0.f;
    avec[jj] = a;                                 // dup lanes write identical value

    const float4* A4 = (const float4*)avec;

    // ---- linear-space forward scan ----
    for (int t = 1; t < L; ++t) {
        const float x = Xl[t * NK + jj];          // independent of avec chain
        float4 v0 = A4[0], v1 = A4[1], v2 = A4[2], v3 = A4[3], v4 = A4[4], v5 = A4[5];
        float s0 = 0.f, s1 = 0.f, s2 = 0.f;
        s0 = fmaf(v0.x, Ecol[ 0], s0); s1 = fmaf(v0.y, Ecol[ 1], s1); s2 = fmaf(v0.z, Ecol[ 2], s2);
        s0 = fmaf(v0.w, Ecol[ 3], s0); s1 = fmaf(v1.x, Ecol[ 4], s1); s2 = fmaf(v1.y, Ecol[ 5], s2);
        s0 = fmaf(v1.z, Ecol[ 6], s0); s1 = fmaf(v1.w, Ecol[ 7], s1); s2 = fmaf(v2.x, Ecol[ 8], s2);
        s0 = fmaf(v2.y, Ecol[ 9], s0); s1 = fmaf(v2.z, Ecol[10], s1); s2 = fmaf(v2.w, Ecol[11], s2);
        s0 = fmaf(v3.x, Ecol[12], s0); s1 = fmaf(v3.y, Ecol[13], s1); s2 = fmaf(v3.z, Ecol[14], s2);
        s0 = fmaf(v3.w, Ecol[15], s0); s1 = fmaf(v4.x, Ecol[16], s1); s2 = fmaf(v4.y, Ecol[17], s2);
        s0 = fmaf(v4.z, Ecol[18], s0); s1 = fmaf(v4.w, Ecol[19], s1); s2 = fmaf(v5.x, Ecol[20], s2);

        a = ((s0 + s1) + s2) * x;

        if ((t & 3) == 0) {                       // renorm by lane-0 value (exact algebra)
            const float m = __uint_as_float(
                __builtin_amdgcn_readfirstlane(__float_as_uint(a)));
            a *= 1.0f / m;
            Orenorm += __logf(m);
        }
        avec[jj] = a;                             // DS in-order per wave: next iter sees it
    }

    // ---- offset sum: Csum = sum_{t<L} C[t] ----
    float cs = 0.f;
    for (int t = lane; t < L; t += 64) cs += C[t];
    #pragma unroll
    for (int off = 32; off > 0; off >>= 1) cs += __shfl_xor(cs, off, 64);

    // ---- logZ = Csum + Orenorm + log(sum_j a_j * exp(end_j)) ----
    float val = (lane < NK) ? a * Eend : 0.f;
    #pragma unroll
    for (int off = 32; off > 0; off >>= 1) val += __shfl_xor(val, off, 64);

    if (lane == 0) per_batch[b] = cs + Orenorm + __logf(val) - num;
}

// ---------------- final reduce: nll = sum_b (logZ_b - num_b) ----------------
__global__ __launch_bounds__(64) void reduce_kernel(
    const float* __restrict__ pb, float* __restrict__ out)
{
    float v = pb[threadIdx.x];
    #pragma unroll
    for (int off = 32; off > 0; off >>= 1) v += __shfl_xor(v, off, 64);
    if (threadIdx.x == 0) out[BSZ * SEQ * NK] = v;
}

extern "C" void kernel_launch(void* const* d_in, const int* in_sizes, int n_in,
                              void* d_out, int out_size, void* d_ws, size_t ws_size,
                              hipStream_t stream)
{
    const float* hidden  = (const float*)d_in[0];
    const float* W       = (const float*)d_in[1];
    const float* bias    = (const float*)d_in[2];
    const float* start_t = (const float*)d_in[3];
    const float* trans   = (const float*)d_in[4];
    const float* end_t   = (const float*)d_in[5];
    const int*   labels  = (const int*)d_in[6];
    const int*   mask    = (const int*)d_in[7];
    float* out = (float*)d_out;
    float* pb  = (float*)d_ws;

    gemm_bias_kernel<<<(BSZ * SEQ) / 64, 256, 0, stream>>>(hidden, W, bias, out);
    crf_kernel<<<BSZ, 64, 0, stream>>>(out, start_t, trans, end_t, labels, mask, pb);
    reduce_kernel<<<1, 64, 0, stream>>>(pb, out);
}

// Round 4
// 291.565 us; speedup vs baseline: 1.5274x; 1.0441x over previous
//
#include <hip/hip_runtime.h>

#define BSZ 64
#define SEQ 512
#define HID 768
#define NK  21

#define REP21(X) X(0) X(1) X(2) X(3) X(4) X(5) X(6) X(7) X(8) X(9) X(10) \
                 X(11) X(12) X(13) X(14) X(15) X(16) X(17) X(18) X(19) X(20)

// ---------------- GEMM + bias: logits = hidden @ W + b ----------------
// Block = 4 waves, 64 rows, 6 chunks of 128 cols. hidden staged into LDS
// column-major hs[col][65] (coalesced global reads, conflict-free LDS r/w).
// Wave q owns col-quarter (wave-uniform W -> scalar loads). Partials via LDS.
__global__ __launch_bounds__(256) void gemm_bias_kernel(
    const float* __restrict__ hidden, const float* __restrict__ W,
    const float* __restrict__ bias, float* __restrict__ out)
{
    __shared__ float hs[128 * 65];                        // 33.3 KB, col-major + pad
    __shared__ float part[4][64 * NK];                    // 21.5 KB

    const int tid  = threadIdx.x;
    const int lane = tid & 63;
    const int wv   = __builtin_amdgcn_readfirstlane(tid >> 6);
    const int cw   = tid & 31;                            // stage: word-col in 32
    const int rr   = tid >> 5;                            // stage: 0..7

    const float* gbase = hidden + (size_t)blockIdx.x * 64 * HID;

#define DECL(i) float a##i = 0.f;
    REP21(DECL)
#undef DECL

    for (int ch = 0; ch < 6; ++ch) {
        __syncthreads();                                  // previous compute done
        const float* gsrc = gbase + ch * 128;
        #pragma unroll
        for (int sub = 0; sub < 4; ++sub) {
            const int col = sub * 32 + cw;
            #pragma unroll
            for (int p = 0; p < 8; ++p) {
                const int row = p * 8 + rr;
                hs[col * 65 + row] = gsrc[(size_t)row * HID + col];
            }
        }
        __syncthreads();                                  // staging visible

        const float* wb   = W + (size_t)(ch * 128 + wv * 32) * NK;  // wave-uniform
        const float* hcol = hs + (size_t)(wv * 32) * 65 + lane;
        #pragma unroll 4
        for (int cc = 0; cc < 32; ++cc) {
            const float h = hcol[cc * 65];
            const float* w = wb + cc * NK;                // wave-uniform -> s_load
#define STEP(i) a##i = fmaf(h, w[i], a##i);
            REP21(STEP)
#undef STEP
        }
    }

    float* pp = &part[wv][lane * NK];
#define ST(i) pp[i] = a##i;
    REP21(ST)
#undef ST
    __syncthreads();

    const int base_out = blockIdx.x * (64 * NK);
    for (int idx = tid; idx < 64 * NK; idx += 256) {
        const int k = idx - (idx / NK) * NK;
        const float s = part[0][idx] + part[1][idx] + part[2][idx] + part[3][idx];
        out[base_out + idx] = s + bias[k];
    }
}

// ---------------- CRF: one wave per batch, linear-space scan ----------------
// All-gather of alpha via v_readlane (VALU speed) -- no LDS in the loop.
__global__ __launch_bounds__(64) void crf_kernel(
    const float* __restrict__ logits,
    const float* __restrict__ start_t,
    const float* __restrict__ trans,
    const float* __restrict__ end_t,
    const int* __restrict__ labels,
    const int* __restrict__ mask,
    float* __restrict__ per_batch)
{
    __shared__ __align__(16) float Xl[SEQ * NK];  // raw logits, then exp(lg - C[t])
    __shared__ float C[SEQ];                      // C[t] = lg[t][0]

    const int b    = blockIdx.x;
    const int lane = threadIdx.x;                 // block = exactly 1 wave

    // ---- stage raw logits (coalesced float4) ----
    {
        const float4* g4 = (const float4*)(logits + (size_t)b * SEQ * NK);
        float4* l4 = (float4*)Xl;
        for (int idx = lane; idx < SEQ * NK / 4; idx += 64) l4[idx] = g4[idx];
    }

    const int* lab = labels + b * SEQ;
    const int* msk = mask   + b * SEQ;

    // ---- sequence length (mask is a prefix of ones) ----
    int cnt = 0;
    for (int t = lane; t < SEQ; t += 64) cnt += (msk[t] != 0);
    #pragma unroll
    for (int off = 32; off > 0; off >>= 1) cnt += __shfl_xor(cnt, off, 64);
    const int L = cnt;

    __syncthreads();  // raw logits staged

    // ---- numerator (gold-path score), wave-parallel over t (raw logits) ----
    float numacc = 0.f;
    for (int t = lane; t < L; t += 64) {
        if (t == 0) numacc += start_t[lab[0]] + Xl[lab[0]];
        else        numacc += Xl[t * NK + lab[t]] + trans[lab[t - 1] * NK + lab[t]];
    }
    if (lane == 0) numacc += end_t[lab[L - 1]];
    #pragma unroll
    for (int off = 32; off > 0; off >>= 1) numacc += __shfl_xor(numacc, off, 64);
    const float num = numacc;

    // ---- extract per-step offsets C[t] = lg[t][0] ----
    for (int t = lane; t < SEQ; t += 64) C[t] = Xl[t * NK];
    __syncthreads();

    // ---- transform in place: Xl[t][j] = exp(lg[t][j] - C[t]) ----
    for (int idx = lane; idx < SEQ * NK; idx += 64) {
        const int t = idx / 21;
        Xl[idx] = __expf(Xl[idx] - C[t]);
    }
    __syncthreads();

    // ---- per-lane constants ----
    const int jj = (lane < NK) ? lane : NK - 1;   // dup lanes >= 21 onto j=20
    float Ecol[NK];
    #pragma unroll
    for (int k = 0; k < NK; ++k) Ecol[k] = __expf(trans[k * NK + jj]);
    const float Eend = __expf(end_t[jj]);

    // ---- init: a_j = exp(start_j) * exp(lg0_j - C[0]) ----
    float a = __expf(start_t[jj]) * Xl[jj];
    float Orenorm = 0.f;

#define RLA(k) __uint_as_float(__builtin_amdgcn_readlane(__float_as_uint(a), k))

    // ---- linear-space forward scan: a'_j = (sum_k a_k E[k][j]) * X[t][j] ----
    #pragma unroll 4
    for (int t = 1; t < L; ++t) {
        const float x = Xl[t * NK + jj];          // LDS read, off the alpha chain
        float s0 = RLA(0) * Ecol[0];
        float s1 = RLA(1) * Ecol[1];
        float s2 = RLA(2) * Ecol[2];
        s0 = fmaf(RLA( 3), Ecol[ 3], s0);
        s1 = fmaf(RLA( 4), Ecol[ 4], s1);
        s2 = fmaf(RLA( 5), Ecol[ 5], s2);
        s0 = fmaf(RLA( 6), Ecol[ 6], s0);
        s1 = fmaf(RLA( 7), Ecol[ 7], s1);
        s2 = fmaf(RLA( 8), Ecol[ 8], s2);
        s0 = fmaf(RLA( 9), Ecol[ 9], s0);
        s1 = fmaf(RLA(10), Ecol[10], s1);
        s2 = fmaf(RLA(11), Ecol[11], s2);
        s0 = fmaf(RLA(12), Ecol[12], s0);
        s1 = fmaf(RLA(13), Ecol[13], s1);
        s2 = fmaf(RLA(14), Ecol[14], s2);
        s0 = fmaf(RLA(15), Ecol[15], s0);
        s1 = fmaf(RLA(16), Ecol[16], s1);
        s2 = fmaf(RLA(17), Ecol[17], s2);
        s0 = fmaf(RLA(18), Ecol[18], s0);
        s1 = fmaf(RLA(19), Ecol[19], s1);
        s2 = fmaf(RLA(20), Ecol[20], s2);

        a = ((s0 + s1) + s2) * x;

        if ((t & 3) == 0) {                       // renorm: mult by r~1/m, add log m
            const float m = __uint_as_float(
                __builtin_amdgcn_readfirstlane(__float_as_uint(a)));
            a *= __builtin_amdgcn_rcpf(m);        // r = (1/m)(1+eps): eps shows up as
            Orenorm += __logf(m);                 // ~1e-7 additive error; negligible
        }
    }
#undef RLA

    // ---- offset sum: Csum = sum_{t<L} C[t] ----
    float cs = 0.f;
    for (int t = lane; t < L; t += 64) cs += C[t];
    #pragma unroll
    for (int off = 32; off > 0; off >>= 1) cs += __shfl_xor(cs, off, 64);

    // ---- logZ = Csum + Orenorm + log(sum_j a_j * exp(end_j)) ----
    float val = (lane < NK) ? a * Eend : 0.f;
    #pragma unroll
    for (int off = 32; off > 0; off >>= 1) val += __shfl_xor(val, off, 64);

    if (lane == 0) per_batch[b] = cs + Orenorm + __logf(val) - num;
}

// ---------------- final reduce: nll = sum_b (logZ_b - num_b) ----------------
__global__ __launch_bounds__(64) void reduce_kernel(
    const float* __restrict__ pb, float* __restrict__ out)
{
    float v = pb[threadIdx.x];
    #pragma unroll
    for (int off = 32; off > 0; off >>= 1) v += __shfl_xor(v, off, 64);
    if (threadIdx.x == 0) out[BSZ * SEQ * NK] = v;
}

extern "C" void kernel_launch(void* const* d_in, const int* in_sizes, int n_in,
                              void* d_out, int out_size, void* d_ws, size_t ws_size,
                              hipStream_t stream)
{
    const float* hidden  = (const float*)d_in[0];
    const float* W       = (const float*)d_in[1];
    const float* bias    = (const float*)d_in[2];
    const float* start_t = (const float*)d_in[3];
    const float* trans   = (const float*)d_in[4];
    const float* end_t   = (const float*)d_in[5];
    const int*   labels  = (const int*)d_in[6];
    const int*   mask    = (const int*)d_in[7];
    float* out = (float*)d_out;
    float* pb  = (float*)d_ws;

    gemm_bias_kernel<<<(BSZ * SEQ) / 64, 256, 0, stream>>>(hidden, W, bias, out);
    crf_kernel<<<BSZ, 64, 0, stream>>>(out, start_t, trans, end_t, labels, mask, pb);
    reduce_kernel<<<1, 64, 0, stream>>>(pb, out);
}

// Round 5
// 250.572 us; speedup vs baseline: 1.7773x; 1.1636x over previous
//
#include <hip/hip_runtime.h>

#define BSZ 64
#define SEQ 512
#define HID 768
#define NK  21

#define REP21(X) X(0) X(1) X(2) X(3) X(4) X(5) X(6) X(7) X(8) X(9) X(10) \
                 X(11) X(12) X(13) X(14) X(15) X(16) X(17) X(18) X(19) X(20)

// ---------------- GEMM + bias: logits = hidden @ W + b ----------------
// UNCHANGED from R4 (kept byte-identical so next round's top-5 shows its
// counters once crf drops below it).
__global__ __launch_bounds__(256) void gemm_bias_kernel(
    const float* __restrict__ hidden, const float* __restrict__ W,
    const float* __restrict__ bias, float* __restrict__ out)
{
    __shared__ float hs[128 * 65];                        // 33.3 KB, col-major + pad
    __shared__ float part[4][64 * NK];                    // 21.5 KB

    const int tid  = threadIdx.x;
    const int lane = tid & 63;
    const int wv   = __builtin_amdgcn_readfirstlane(tid >> 6);
    const int cw   = tid & 31;                            // stage: word-col in 32
    const int rr   = tid >> 5;                            // stage: 0..7

    const float* gbase = hidden + (size_t)blockIdx.x * 64 * HID;

#define DECL(i) float a##i = 0.f;
    REP21(DECL)
#undef DECL

    for (int ch = 0; ch < 6; ++ch) {
        __syncthreads();                                  // previous compute done
        const float* gsrc = gbase + ch * 128;
        #pragma unroll
        for (int sub = 0; sub < 4; ++sub) {
            const int col = sub * 32 + cw;
            #pragma unroll
            for (int p = 0; p < 8; ++p) {
                const int row = p * 8 + rr;
                hs[col * 65 + row] = gsrc[(size_t)row * HID + col];
            }
        }
        __syncthreads();                                  // staging visible

        const float* wb   = W + (size_t)(ch * 128 + wv * 32) * NK;  // wave-uniform
        const float* hcol = hs + (size_t)(wv * 32) * 65 + lane;
        #pragma unroll 4
        for (int cc = 0; cc < 32; ++cc) {
            const float h = hcol[cc * 65];
            const float* w = wb + cc * NK;                // wave-uniform -> s_load
#define STEP(i) a##i = fmaf(h, w[i], a##i);
            REP21(STEP)
#undef STEP
        }
    }

    float* pp = &part[wv][lane * NK];
#define ST(i) pp[i] = a##i;
    REP21(ST)
#undef ST
    __syncthreads();

    const int base_out = blockIdx.x * (64 * NK);
    for (int idx = tid; idx < 64 * NK; idx += 256) {
        const int k = idx - (idx / NK) * NK;
        const float s = part[0][idx] + part[1][idx] + part[2][idx] + part[3][idx];
        out[base_out + idx] = s + bias[k];
    }
}

// ---------------- CRF: 2 waves per batch (forward + backward) ----------------
// Exact identity: Z = sum_i alpha_m[i] * beta_m[i] at midpoint m.
// Linear space with per-step offsets C[t]=lg[t][0] and periodic renorm.
__global__ __launch_bounds__(128) void crf_kernel(
    const float* __restrict__ logits,
    const float* __restrict__ start_t,
    const float* __restrict__ trans,
    const float* __restrict__ end_t,
    const int* __restrict__ labels,
    const int* __restrict__ mask,
    float* __restrict__ per_batch)
{
    __shared__ __align__(16) float Xl[SEQ * NK];  // raw logits -> exp(lg - C[t])
    __shared__ float C[SEQ];                      // C[t] = lg[t][0]
    __shared__ float comb[24];                    // [0..20] beta_m, [21] OB, [22/23] num parts

    const int b    = blockIdx.x;
    const int tid  = threadIdx.x;                 // 0..127
    const int lane = tid & 63;
    const int wid  = tid >> 6;                    // 0 = forward, 1 = backward

    // ---- stage raw logits (coalesced float4, both waves) ----
    {
        const float4* g4 = (const float4*)(logits + (size_t)b * SEQ * NK);
        float4* l4 = (float4*)Xl;
        for (int idx = tid; idx < SEQ * NK / 4; idx += 128) l4[idx] = g4[idx];
    }

    const int* lab = labels + b * SEQ;
    const int* msk = mask   + b * SEQ;

    // ---- sequence length (per wave, mask is a prefix of ones) ----
    int cnt = 0;
    for (int t = lane; t < SEQ; t += 64) cnt += (msk[t] != 0);
    #pragma unroll
    for (int off = 32; off > 0; off >>= 1) cnt += __shfl_xor(cnt, off, 64);
    const int L = cnt;
    const int m = L >> 1;                         // midpoint cut

    __syncthreads();                              // staging visible

    // ---- numerator partials (raw Xl), split across 128 threads ----
    {
        float numacc = 0.f;
        for (int t = tid; t < L; t += 128) {
            if (t == 0) numacc += start_t[lab[0]] + Xl[lab[0]];
            else        numacc += Xl[t * NK + lab[t]] + trans[lab[t - 1] * NK + lab[t]];
        }
        if (tid == 0) numacc += end_t[lab[L - 1]];
        #pragma unroll
        for (int off = 32; off > 0; off >>= 1) numacc += __shfl_xor(numacc, off, 64);
        if (lane == 0) comb[22 + wid] = numacc;
    }

    // ---- extract per-step offsets C[t] ----
    for (int t = tid; t < SEQ; t += 128) C[t] = Xl[t * NK];
    __syncthreads();                              // C complete before transform

    // ---- transform in place: Xl[t][j] = exp(lg[t][j] - C[t]) ----
    for (int idx = tid; idx < SEQ * NK; idx += 128) {
        const int t = idx / NK;
        Xl[idx] = __expf(Xl[idx] - C[t]);
    }
    __syncthreads();                              // transformed Xl visible

    const int jj = (lane < NK) ? lane : NK - 1;   // dup lanes >= 21 onto j=20

#define RL(v, k) __uint_as_float(__builtin_amdgcn_readlane(__float_as_uint(v), k))

    float a;                                      // alpha (fwd) / beta (bwd), linear
    float Orenorm = 0.f;
    float csum = 0.f;

    if (wid == 0) {
        // ================= FORWARD: alpha_0 .. alpha_m =================
        float Ecol[NK];                           // E[i][jj]
        #pragma unroll
        for (int k = 0; k < NK; ++k) Ecol[k] = __expf(trans[k * NK + jj]);

        a = __expf(start_t[jj]) * Xl[jj];         // alpha_0 (linear, offset C[0])
        for (int t = lane; t <= m; t += 64) csum += C[t];

        // depth-2 prefetch of emissions (reads always in-bounds: m+2 <= 258)
        float xv = Xl[NK + jj];
        float xn = Xl[2 * NK + jj];
        for (int t = 1; t <= m; ++t) {
            const float xn2 = Xl[(t + 2) * NK + jj];
            float s0 = RL(a, 0) * Ecol[0];
            float s1 = RL(a, 1) * Ecol[1];
            float s2 = RL(a, 2) * Ecol[2];
            s0 = fmaf(RL(a,  3), Ecol[ 3], s0);
            s1 = fmaf(RL(a,  4), Ecol[ 4], s1);
            s2 = fmaf(RL(a,  5), Ecol[ 5], s2);
            s0 = fmaf(RL(a,  6), Ecol[ 6], s0);
            s1 = fmaf(RL(a,  7), Ecol[ 7], s1);
            s2 = fmaf(RL(a,  8), Ecol[ 8], s2);
            s0 = fmaf(RL(a,  9), Ecol[ 9], s0);
            s1 = fmaf(RL(a, 10), Ecol[10], s1);
            s2 = fmaf(RL(a, 11), Ecol[11], s2);
            s0 = fmaf(RL(a, 12), Ecol[12], s0);
            s1 = fmaf(RL(a, 13), Ecol[13], s1);
            s2 = fmaf(RL(a, 14), Ecol[14], s2);
            s0 = fmaf(RL(a, 15), Ecol[15], s0);
            s1 = fmaf(RL(a, 16), Ecol[16], s1);
            s2 = fmaf(RL(a, 17), Ecol[17], s2);
            s0 = fmaf(RL(a, 18), Ecol[18], s0);
            s1 = fmaf(RL(a, 19), Ecol[19], s1);
            s2 = fmaf(RL(a, 20), Ecol[20], s2);
            a = ((s0 + s1) + s2) * xv;
            if ((t & 7) == 0) {                   // renorm every 8 (exact algebra)
                const float mm = __uint_as_float(
                    __builtin_amdgcn_readfirstlane(__float_as_uint(a)));
                a *= __builtin_amdgcn_rcpf(mm);
                Orenorm += __logf(mm);
            }
            xv = xn; xn = xn2;
        }
    } else {
        // ================= BACKWARD: beta_{L-1} .. beta_m =================
        float Erow[NK];                           // E[jj][k]
        #pragma unroll
        for (int k = 0; k < NK; ++k) Erow[k] = __expf(trans[jj * NK + k]);

        a = __expf(end_t[jj]);                    // beta_{L-1}
        for (int t = m + 1 + lane; t < L; t += 64) csum += C[t];

        float xv = Xl[(L - 1) * NK + jj];
        float xn = Xl[max(L - 2, 0) * NK + jj];
        for (int t = L - 1; t > m; --t) {
            const float xn2 = Xl[max(t - 2, 0) * NK + jj];
            const float u = a * xv;               // u_j = beta_j * X_t[j]
            float s0 = RL(u, 0) * Erow[0];
            float s1 = RL(u, 1) * Erow[1];
            float s2 = RL(u, 2) * Erow[2];
            s0 = fmaf(RL(u,  3), Erow[ 3], s0);
            s1 = fmaf(RL(u,  4), Erow[ 4], s1);
            s2 = fmaf(RL(u,  5), Erow[ 5], s2);
            s0 = fmaf(RL(u,  6), Erow[ 6], s0);
            s1 = fmaf(RL(u,  7), Erow[ 7], s1);
            s2 = fmaf(RL(u,  8), Erow[ 8], s2);
            s0 = fmaf(RL(u,  9), Erow[ 9], s0);
            s1 = fmaf(RL(u, 10), Erow[10], s1);
            s2 = fmaf(RL(u, 11), Erow[11], s2);
            s0 = fmaf(RL(u, 12), Erow[12], s0);
            s1 = fmaf(RL(u, 13), Erow[13], s1);
            s2 = fmaf(RL(u, 14), Erow[14], s2);
            s0 = fmaf(RL(u, 15), Erow[15], s0);
            s1 = fmaf(RL(u, 16), Erow[16], s1);
            s2 = fmaf(RL(u, 17), Erow[17], s2);
            s0 = fmaf(RL(u, 18), Erow[18], s0);
            s1 = fmaf(RL(u, 19), Erow[19], s1);
            s2 = fmaf(RL(u, 20), Erow[20], s2);
            a = (s0 + s1) + s2;
            if ((t & 7) == 0) {
                const float mm = __uint_as_float(
                    __builtin_amdgcn_readfirstlane(__float_as_uint(a)));
                a *= __builtin_amdgcn_rcpf(mm);
                Orenorm += __logf(mm);
            }
            xv = xn; xn = xn2;
        }
    }
#undef RL

    // ---- wave-reduce csum ----
    #pragma unroll
    for (int off = 32; off > 0; off >>= 1) csum += __shfl_xor(csum, off, 64);

    if (wid == 1) {                               // publish beta_m and OB
        if (lane < NK) comb[lane] = a;
        if (lane == 0) comb[21] = csum + Orenorm;
    }
    __syncthreads();

    if (wid == 0) {
        // logZ = OF + OB + log(sum_j alpha_m[j] * beta_m[j])
        float val = (lane < NK) ? a * comb[lane] : 0.f;
        #pragma unroll
        for (int off = 32; off > 0; off >>= 1) val += __shfl_xor(val, off, 64);
        if (lane == 0) {
            const float OF  = csum + Orenorm;
            const float num = comb[22] + comb[23];
            per_batch[b] = OF + comb[21] + __logf(val) - num;
        }
    }
}

// ---------------- final reduce: nll = sum_b (logZ_b - num_b) ----------------
__global__ __launch_bounds__(64) void reduce_kernel(
    const float* __restrict__ pb, float* __restrict__ out)
{
    float v = pb[threadIdx.x];
    #pragma unroll
    for (int off = 32; off > 0; off >>= 1) v += __shfl_xor(v, off, 64);
    if (threadIdx.x == 0) out[BSZ * SEQ * NK] = v;
}

extern "C" void kernel_launch(void* const* d_in, const int* in_sizes, int n_in,
                              void* d_out, int out_size, void* d_ws, size_t ws_size,
                              hipStream_t stream)
{
    const float* hidden  = (const float*)d_in[0];
    const float* W       = (const float*)d_in[1];
    const float* bias    = (const float*)d_in[2];
    const float* start_t = (const float*)d_in[3];
    const float* trans   = (const float*)d_in[4];
    const float* end_t   = (const float*)d_in[5];
    const int*   labels  = (const int*)d_in[6];
    const int*   mask    = (const int*)d_in[7];
    float* out = (float*)d_out;
    float* pb  = (float*)d_ws;

    gemm_bias_kernel<<<(BSZ * SEQ) / 64, 256, 0, stream>>>(hidden, W, bias, out);
    crf_kernel<<<BSZ, 128, 0, stream>>>(out, start_t, trans, end_t, labels, mask, pb);
    reduce_kernel<<<1, 64, 0, stream>>>(pb, out);
}

// Round 6
// 234.445 us; speedup vs baseline: 1.8996x; 1.0688x over previous
//
#include <hip/hip_runtime.h>

#define BSZ 64
#define SEQ 512
#define HID 768
#define NK  21

#define REP21(X) X(0) X(1) X(2) X(3) X(4) X(5) X(6) X(7) X(8) X(9) X(10) \
                 X(11) X(12) X(13) X(14) X(15) X(16) X(17) X(18) X(19) X(20)

// ---------------- GEMM + bias: logits = hidden @ W + b ----------------
// Block = 4 waves, 64 rows, 12 chunks of 64 cols, DOUBLE-BUFFERED LDS:
// chunk ch+1 is loaded into VGPR temps while chunk ch computes; one barrier
// per chunk. hs col-major (conflict-free), W wave-uniform -> s_load.
__global__ __launch_bounds__(256) void gemm_bias_kernel(
    const float* __restrict__ hidden, const float* __restrict__ W,
    const float* __restrict__ bias, float* __restrict__ out)
{
    __shared__ float hs[2][64 * 65];                      // 33.3 KB (2 bufs)
    __shared__ float part[4][64 * NK];                    // 21.5 KB

    const int tid  = threadIdx.x;
    const int lane = tid & 63;
    const int wv   = __builtin_amdgcn_readfirstlane(tid >> 6);
    const int cw   = tid & 31;                            // stage col-in-32
    const int rr   = tid >> 5;                            // stage row 0..7

    const float* gbase = hidden + (size_t)blockIdx.x * 64 * HID;

#define DECL(i) float a##i = 0.f;
    REP21(DECL)
#undef DECL

    float st[16];                                         // staging temps
    // preload chunk 0
    #pragma unroll
    for (int sub = 0; sub < 2; ++sub)
        #pragma unroll
        for (int p = 0; p < 8; ++p)
            st[sub * 8 + p] = gbase[(size_t)(p * 8 + rr) * HID + sub * 32 + cw];

    for (int ch = 0; ch < 12; ++ch) {
        float* hb = hs[ch & 1];
        // regs -> LDS (conflict-free col-major write)
        #pragma unroll
        for (int sub = 0; sub < 2; ++sub)
            #pragma unroll
            for (int p = 0; p < 8; ++p)
                hb[(sub * 32 + cw) * 65 + p * 8 + rr] = st[sub * 8 + p];
        __syncthreads();                                  // buffer visible; other buf free

        if (ch < 11) {                                    // loads overlap compute below
            const float* gsrc = gbase + (ch + 1) * 64;
            #pragma unroll
            for (int sub = 0; sub < 2; ++sub)
                #pragma unroll
                for (int p = 0; p < 8; ++p)
                    st[sub * 8 + p] = gsrc[(size_t)(p * 8 + rr) * HID + sub * 32 + cw];
        }

        const float* wb   = W + (size_t)(ch * 64 + wv * 16) * NK;   // wave-uniform
        const float* hcol = hb + (size_t)(wv * 16) * 65 + lane;
        #pragma unroll 4
        for (int cc = 0; cc < 16; ++cc) {
            const float h = hcol[cc * 65];
            const float* w = wb + cc * NK;                // wave-uniform -> s_load
#define STEP(i) a##i = fmaf(h, w[i], a##i);
            REP21(STEP)
#undef STEP
        }
        // no trailing barrier: next write goes to the other buffer; the next
        // barrier orders it against everyone's compute of this chunk.
    }

    float* pp = &part[wv][lane * NK];
#define ST(i) pp[i] = a##i;
    REP21(ST)
#undef ST
    __syncthreads();

    const int base_out = blockIdx.x * (64 * NK);
    for (int idx = tid; idx < 64 * NK; idx += 256) {
        const int k = idx - (idx / NK) * NK;
        const float s = part[0][idx] + part[1][idx] + part[2][idx] + part[3][idx];
        out[base_out + idx] = s + bias[k];
    }
}

// ---------------- CRF: 2 waves per batch (forward + backward) ----------------
// Z = sum_i alpha_m[i] * beta_m[i] at midpoint m. Linear space, offsets
// C[t]=lg[t][0], renorm once per 8-step group. Branchless unroll-8 body:
// all 8 emission LDS reads issue together.
__global__ __launch_bounds__(128) void crf_kernel(
    const float* __restrict__ logits,
    const float* __restrict__ start_t,
    const float* __restrict__ trans,
    const float* __restrict__ end_t,
    const int* __restrict__ labels,
    const int* __restrict__ mask,
    float* __restrict__ per_batch)
{
    __shared__ __align__(16) float Xl[SEQ * NK];  // raw logits -> exp(lg - C[t])
    __shared__ float C[SEQ];                      // C[t] = lg[t][0]
    __shared__ float comb[24];                    // beta_m, OB, num parts

    const int b    = blockIdx.x;
    const int tid  = threadIdx.x;                 // 0..127
    const int lane = tid & 63;
    const int wid  = tid >> 6;                    // 0 = forward, 1 = backward

    {   // stage raw logits (coalesced float4, both waves)
        const float4* g4 = (const float4*)(logits + (size_t)b * SEQ * NK);
        float4* l4 = (float4*)Xl;
        for (int idx = tid; idx < SEQ * NK / 4; idx += 128) l4[idx] = g4[idx];
    }

    const int* lab = labels + b * SEQ;
    const int* msk = mask   + b * SEQ;

    // sequence length (mask is a prefix of ones)
    int cnt = 0;
    for (int t = lane; t < SEQ; t += 64) cnt += (msk[t] != 0);
    #pragma unroll
    for (int off = 32; off > 0; off >>= 1) cnt += __shfl_xor(cnt, off, 64);
    const int L = cnt;
    const int m = L >> 1;

    __syncthreads();

    {   // numerator partials (raw Xl)
        float numacc = 0.f;
        for (int t = tid; t < L; t += 128) {
            if (t == 0) numacc += start_t[lab[0]] + Xl[lab[0]];
            else        numacc += Xl[t * NK + lab[t]] + trans[lab[t - 1] * NK + lab[t]];
        }
        if (tid == 0) numacc += end_t[lab[L - 1]];
        #pragma unroll
        for (int off = 32; off > 0; off >>= 1) numacc += __shfl_xor(numacc, off, 64);
        if (lane == 0) comb[22 + wid] = numacc;
    }

    for (int t = tid; t < SEQ; t += 128) C[t] = Xl[t * NK];
    __syncthreads();

    for (int idx = tid; idx < SEQ * NK; idx += 128) {
        const int t = idx / NK;
        Xl[idx] = __expf(Xl[idx] - C[t]);
    }
    __syncthreads();

    const int jj = (lane < NK) ? lane : NK - 1;

#define RL(v, k) __uint_as_float(__builtin_amdgcn_readlane(__float_as_uint(v), k))
#define MATVEC(vv, EE, outv) do {                                          \
    float s0 = RL(vv, 0) * EE[0];                                          \
    float s1 = RL(vv, 1) * EE[1];                                          \
    float s2 = RL(vv, 2) * EE[2];                                          \
    s0 = fmaf(RL(vv,  3), EE[ 3], s0); s1 = fmaf(RL(vv,  4), EE[ 4], s1);  \
    s2 = fmaf(RL(vv,  5), EE[ 5], s2); s0 = fmaf(RL(vv,  6), EE[ 6], s0);  \
    s1 = fmaf(RL(vv,  7), EE[ 7], s1); s2 = fmaf(RL(vv,  8), EE[ 8], s2);  \
    s0 = fmaf(RL(vv,  9), EE[ 9], s0); s1 = fmaf(RL(vv, 10), EE[10], s1);  \
    s2 = fmaf(RL(vv, 11), EE[11], s2); s0 = fmaf(RL(vv, 12), EE[12], s0);  \
    s1 = fmaf(RL(vv, 13), EE[13], s1); s2 = fmaf(RL(vv, 14), EE[14], s2);  \
    s0 = fmaf(RL(vv, 15), EE[15], s0); s1 = fmaf(RL(vv, 16), EE[16], s1);  \
    s2 = fmaf(RL(vv, 17), EE[17], s2); s0 = fmaf(RL(vv, 18), EE[18], s0);  \
    s1 = fmaf(RL(vv, 19), EE[19], s1); s2 = fmaf(RL(vv, 20), EE[20], s2);  \
    outv = (s0 + s1) + s2;                                                 \
} while (0)
#define RENORM() do {                                                      \
    const float mm = __uint_as_float(                                      \
        __builtin_amdgcn_readfirstlane(__float_as_uint(a)));               \
    a *= __builtin_amdgcn_rcpf(mm);                                        \
    Orenorm += __logf(mm);                                                 \
} while (0)

    float a;
    float Orenorm = 0.f;
    float csum = 0.f;

    if (wid == 0) {
        // ---------------- FORWARD: alpha_0 .. alpha_m ----------------
        float Ecol[NK];
        #pragma unroll
        for (int k = 0; k < NK; ++k) Ecol[k] = __expf(trans[k * NK + jj]);

        a = __expf(start_t[jj]) * Xl[jj];
        for (int t = lane; t <= m; t += 64) csum += C[t];

#define FSTEP(xr) do { float nv; MATVEC(a, Ecol, nv); a = nv * (xr); } while (0)
        int t0 = 1;
        for (; t0 + 7 <= m; t0 += 8) {
            const float* xb = Xl + t0 * NK + jj;
            const float x0 = xb[0];      const float x1 = xb[NK];
            const float x2 = xb[2 * NK]; const float x3 = xb[3 * NK];
            const float x4 = xb[4 * NK]; const float x5 = xb[5 * NK];
            const float x6 = xb[6 * NK]; const float x7 = xb[7 * NK];
            FSTEP(x0); FSTEP(x1); FSTEP(x2); FSTEP(x3);
            FSTEP(x4); FSTEP(x5); FSTEP(x6); FSTEP(x7);
            RENORM();
        }
        for (; t0 <= m; ++t0) { const float x = Xl[t0 * NK + jj]; FSTEP(x); }
#undef FSTEP
    } else {
        // ---------------- BACKWARD: beta_{L-1} .. beta_m ----------------
        float Erow[NK];
        #pragma unroll
        for (int k = 0; k < NK; ++k) Erow[k] = __expf(trans[jj * NK + k]);

        a = __expf(end_t[jj]);
        for (int t = m + 1 + lane; t < L; t += 64) csum += C[t];

#define BSTEP(xr) do { const float u = a * (xr); float nv; MATVEC(u, Erow, nv); a = nv; } while (0)
        int t0 = L - 1;
        for (; t0 - 7 >= m + 1; t0 -= 8) {
            const float* xb = Xl + t0 * NK + jj;
            const float x0 = xb[0];       const float x1 = xb[-NK];
            const float x2 = xb[-2 * NK]; const float x3 = xb[-3 * NK];
            const float x4 = xb[-4 * NK]; const float x5 = xb[-5 * NK];
            const float x6 = xb[-6 * NK]; const float x7 = xb[-7 * NK];
            BSTEP(x0); BSTEP(x1); BSTEP(x2); BSTEP(x3);
            BSTEP(x4); BSTEP(x5); BSTEP(x6); BSTEP(x7);
            RENORM();
        }
        for (; t0 >= m + 1; --t0) { const float x = Xl[t0 * NK + jj]; BSTEP(x); }
#undef BSTEP
    }
#undef RL
#undef MATVEC
#undef RENORM

    #pragma unroll
    for (int off = 32; off > 0; off >>= 1) csum += __shfl_xor(csum, off, 64);

    if (wid == 1) {
        if (lane < NK) comb[lane] = a;
        if (lane == 0) comb[21] = csum + Orenorm;
    }
    __syncthreads();

    if (wid == 0) {
        float val = (lane < NK) ? a * comb[lane] : 0.f;
        #pragma unroll
        for (int off = 32; off > 0; off >>= 1) val += __shfl_xor(val, off, 64);
        if (lane == 0) {
            const float OF  = csum + Orenorm;
            const float num = comb[22] + comb[23];
            per_batch[b] = OF + comb[21] + __logf(val) - num;
        }
    }
}

// ---------------- final reduce: nll = sum_b (logZ_b - num_b) ----------------
__global__ __launch_bounds__(64) void reduce_kernel(
    const float* __restrict__ pb, float* __restrict__ out)
{
    float v = pb[threadIdx.x];
    #pragma unroll
    for (int off = 32; off > 0; off >>= 1) v += __shfl_xor(v, off, 64);
    if (threadIdx.x == 0) out[BSZ * SEQ * NK] = v;
}

extern "C" void kernel_launch(void* const* d_in, const int* in_sizes, int n_in,
                              void* d_out, int out_size, void* d_ws, size_t ws_size,
                              hipStream_t stream)
{
    const float* hidden  = (const float*)d_in[0];
    const float* W       = (const float*)d_in[1];
    const float* bias    = (const float*)d_in[2];
    const float* start_t = (const float*)d_in[3];
    const float* trans   = (const float*)d_in[4];
    const float* end_t   = (const float*)d_in[5];
    const int*   labels  = (const int*)d_in[6];
    const int*   mask    = (const int*)d_in[7];
    float* out = (float*)d_out;
    float* pb  = (float*)d_ws;

    gemm_bias_kernel<<<(BSZ * SEQ) / 64, 256, 0, stream>>>(hidden, W, bias, out);
    crf_kernel<<<BSZ, 128, 0, stream>>>(out, start_t, trans, end_t, labels, mask, pb);
    reduce_kernel<<<1, 64, 0, stream>>>(pb, out);
}

// Round 7
// 209.019 us; speedup vs baseline: 2.1307x; 1.1216x over previous
//
#include <hip/hip_runtime.h>

#define BSZ 64
#define SEQ 512
#define HID 768
#define NK  21

typedef short bf16x8 __attribute__((ext_vector_type(8)));
typedef float f32x4  __attribute__((ext_vector_type(4)));

__device__ __forceinline__ unsigned f2bf_pk(float lo, float hi) {
    // RNE fp32->bf16, packed two to a dword (lo in low half)
    unsigned ul = __float_as_uint(lo);
    unsigned uh = __float_as_uint(hi);
    ul = (ul + 0x7fffu + ((ul >> 16) & 1u)) >> 16;
    uh = (uh + 0x7fffu + ((uh >> 16) & 1u)) >> 16;
    return ul | (uh << 16);
}

// ---------------- GEMM + bias: logits = hidden @ W + b (bf16 MFMA) ----------
// Block = 256 thr = 4 waves; wave = one 16-row M-tile (block covers 64 rows).
// A-frags: direct global->VGPR (lanes m,m+16,m+32,m+48 cover 128 contiguous
// bytes of row m), converted to bf16 in-register. B: W staged once to LDS as
// bf16 WlT[n][k] (stride 784), B-frag = one ds_read_b128. N=21 padded to 32;
// cols 21..31 hold garbage but MFMA columns are independent and never stored.
#define WSTRIDE 784
__global__ __launch_bounds__(256) void gemm_bias_kernel(
    const float* __restrict__ hidden, const float* __restrict__ W,
    const float* __restrict__ bias, float* __restrict__ out)
{
    __shared__ unsigned short WlT[32 * WSTRIDE];          // 50.2 KB

    const int tid  = threadIdx.x;
    const int lane = tid & 63;
    const int wv   = tid >> 6;
    const int n    = lane & 15;                           // N (B/C/D) | M (A)
    const int quad = lane >> 4;                           // k-subchunk owner

    const int arow = blockIdx.x * 64 + wv * 16 + n;       // A: m = lane&15
    const float* ap = hidden + (size_t)arow * HID + quad * 8;

    // chunk-0 A prefetch (before W staging: independent of LDS)
    float4 c0a = *(const float4*)(ap + 0);
    float4 c0b = *(const float4*)(ap + 4);

    // ---- stage W -> LDS bf16, transposed [n][k] ----
    for (int idx = tid; idx < HID * NK; idx += 256) {
        const int k = idx / NK;
        const int nn = idx - k * NK;
        const unsigned u = __float_as_uint(W[idx]);
        WlT[nn * WSTRIDE + k] =
            (unsigned short)((u + 0x7fffu + ((u >> 16) & 1u)) >> 16);
    }
    __syncthreads();

    const unsigned short* bp0 = WlT + n * WSTRIDE + quad * 8;          // ntile 0
    const unsigned short* bp1 = WlT + (16 + n) * WSTRIDE + quad * 8;   // ntile 1

    f32x4 acc0 = {0.f, 0.f, 0.f, 0.f};
    f32x4 acc1 = {0.f, 0.f, 0.f, 0.f};

    #pragma unroll
    for (int c = 0; c < HID / 32; ++c) {                  // 24 K-chunks
        float4 c1a, c1b;
        if (c + 1 < HID / 32) {                           // depth-2 A prefetch
            c1a = *(const float4*)(ap + (c + 1) * 32);
            c1b = *(const float4*)(ap + (c + 1) * 32 + 4);
        }
        union { bf16x8 v; unsigned u[4]; } af;
        af.u[0] = f2bf_pk(c0a.x, c0a.y);
        af.u[1] = f2bf_pk(c0a.z, c0a.w);
        af.u[2] = f2bf_pk(c0b.x, c0b.y);
        af.u[3] = f2bf_pk(c0b.z, c0b.w);

        const bf16x8 b0 = *(const bf16x8*)(bp0 + c * 32);
        const bf16x8 b1 = *(const bf16x8*)(bp1 + c * 32);

        acc0 = __builtin_amdgcn_mfma_f32_16x16x32_bf16(af.v, b0, acc0, 0, 0, 0);
        acc1 = __builtin_amdgcn_mfma_f32_16x16x32_bf16(af.v, b1, acc1, 0, 0, 0);
        c0a = c1a; c0b = c1b;
    }

    // ---- epilogue: C/D layout col=lane&15, row=quad*4+reg ----
    const float b0v = bias[n];
    const float b1v = (n < NK - 16) ? bias[16 + n] : 0.f;
    const int rbase = blockIdx.x * 64 + wv * 16 + quad * 4;
    #pragma unroll
    for (int r = 0; r < 4; ++r) {
        float* op = out + (size_t)(rbase + r) * NK;
        op[n] = acc0[r] + b0v;
        if (n < NK - 16) op[16 + n] = acc1[r] + b1v;
    }
}

// ---------------- CRF: 2 waves per batch (forward + backward) ----------------
// UNCHANGED from R6.
__global__ __launch_bounds__(128) void crf_kernel(
    const float* __restrict__ logits,
    const float* __restrict__ start_t,
    const float* __restrict__ trans,
    const float* __restrict__ end_t,
    const int* __restrict__ labels,
    const int* __restrict__ mask,
    float* __restrict__ per_batch)
{
    __shared__ __align__(16) float Xl[SEQ * NK];  // raw logits -> exp(lg - C[t])
    __shared__ float C[SEQ];                      // C[t] = lg[t][0]
    __shared__ float comb[24];                    // beta_m, OB, num parts

    const int b    = blockIdx.x;
    const int tid  = threadIdx.x;                 // 0..127
    const int lane = tid & 63;
    const int wid  = tid >> 6;                    // 0 = forward, 1 = backward

    {   // stage raw logits (coalesced float4, both waves)
        const float4* g4 = (const float4*)(logits + (size_t)b * SEQ * NK);
        float4* l4 = (float4*)Xl;
        for (int idx = tid; idx < SEQ * NK / 4; idx += 128) l4[idx] = g4[idx];
    }

    const int* lab = labels + b * SEQ;
    const int* msk = mask   + b * SEQ;

    // sequence length (mask is a prefix of ones)
    int cnt = 0;
    for (int t = lane; t < SEQ; t += 64) cnt += (msk[t] != 0);
    #pragma unroll
    for (int off = 32; off > 0; off >>= 1) cnt += __shfl_xor(cnt, off, 64);
    const int L = cnt;
    const int m = L >> 1;

    __syncthreads();

    {   // numerator partials (raw Xl)
        float numacc = 0.f;
        for (int t = tid; t < L; t += 128) {
            if (t == 0) numacc += start_t[lab[0]] + Xl[lab[0]];
            else        numacc += Xl[t * NK + lab[t]] + trans[lab[t - 1] * NK + lab[t]];
        }
        if (tid == 0) numacc += end_t[lab[L - 1]];
        #pragma unroll
        for (int off = 32; off > 0; off >>= 1) numacc += __shfl_xor(numacc, off, 64);
        if (lane == 0) comb[22 + wid] = numacc;
    }

    for (int t = tid; t < SEQ; t += 128) C[t] = Xl[t * NK];
    __syncthreads();

    for (int idx = tid; idx < SEQ * NK; idx += 128) {
        const int t = idx / NK;
        Xl[idx] = __expf(Xl[idx] - C[t]);
    }
    __syncthreads();

    const int jj = (lane < NK) ? lane : NK - 1;

#define RL(v, k) __uint_as_float(__builtin_amdgcn_readlane(__float_as_uint(v), k))
#define MATVEC(vv, EE, outv) do {                                          \
    float s0 = RL(vv, 0) * EE[0];                                          \
    float s1 = RL(vv, 1) * EE[1];                                          \
    float s2 = RL(vv, 2) * EE[2];                                          \
    s0 = fmaf(RL(vv,  3), EE[ 3], s0); s1 = fmaf(RL(vv,  4), EE[ 4], s1);  \
    s2 = fmaf(RL(vv,  5), EE[ 5], s2); s0 = fmaf(RL(vv,  6), EE[ 6], s0);  \
    s1 = fmaf(RL(vv,  7), EE[ 7], s1); s2 = fmaf(RL(vv,  8), EE[ 8], s2);  \
    s0 = fmaf(RL(vv,  9), EE[ 9], s0); s1 = fmaf(RL(vv, 10), EE[10], s1);  \
    s2 = fmaf(RL(vv, 11), EE[11], s2); s0 = fmaf(RL(vv, 12), EE[12], s0);  \
    s1 = fmaf(RL(vv, 13), EE[13], s1); s2 = fmaf(RL(vv, 14), EE[14], s2);  \
    s0 = fmaf(RL(vv, 15), EE[15], s0); s1 = fmaf(RL(vv, 16), EE[16], s1);  \
    s2 = fmaf(RL(vv, 17), EE[17], s2); s0 = fmaf(RL(vv, 18), EE[18], s0);  \
    s1 = fmaf(RL(vv, 19), EE[19], s1); s2 = fmaf(RL(vv, 20), EE[20], s2);  \
    outv = (s0 + s1) + s2;                                                 \
} while (0)
#define RENORM() do {                                                      \
    const float mm = __uint_as_float(                                      \
        __builtin_amdgcn_readfirstlane(__float_as_uint(a)));               \
    a *= __builtin_amdgcn_rcpf(mm);                                        \
    Orenorm += __logf(mm);                                                 \
} while (0)

    float a;
    float Orenorm = 0.f;
    float csum = 0.f;

    if (wid == 0) {
        // ---------------- FORWARD: alpha_0 .. alpha_m ----------------
        float Ecol[NK];
        #pragma unroll
        for (int k = 0; k < NK; ++k) Ecol[k] = __expf(trans[k * NK + jj]);

        a = __expf(start_t[jj]) * Xl[jj];
        for (int t = lane; t <= m; t += 64) csum += C[t];

#define FSTEP(xr) do { float nv; MATVEC(a, Ecol, nv); a = nv * (xr); } while (0)
        int t0 = 1;
        for (; t0 + 7 <= m; t0 += 8) {
            const float* xb = Xl + t0 * NK + jj;
            const float x0 = xb[0];      const float x1 = xb[NK];
            const float x2 = xb[2 * NK]; const float x3 = xb[3 * NK];
            const float x4 = xb[4 * NK]; const float x5 = xb[5 * NK];
            const float x6 = xb[6 * NK]; const float x7 = xb[7 * NK];
            FSTEP(x0); FSTEP(x1); FSTEP(x2); FSTEP(x3);
            FSTEP(x4); FSTEP(x5); FSTEP(x6); FSTEP(x7);
            RENORM();
        }
        for (; t0 <= m; ++t0) { const float x = Xl[t0 * NK + jj]; FSTEP(x); }
#undef FSTEP
    } else {
        // ---------------- BACKWARD: beta_{L-1} .. beta_m ----------------
        float Erow[NK];
        #pragma unroll
        for (int k = 0; k < NK; ++k) Erow[k] = __expf(trans[jj * NK + k]);

        a = __expf(end_t[jj]);
        for (int t = m + 1 + lane; t < L; t += 64) csum += C[t];

#define BSTEP(xr) do { const float u = a * (xr); float nv; MATVEC(u, Erow, nv); a = nv; } while (0)
        int t0 = L - 1;
        for (; t0 - 7 >= m + 1; t0 -= 8) {
            const float* xb = Xl + t0 * NK + jj;
            const float x0 = xb[0];       const float x1 = xb[-NK];
            const float x2 = xb[-2 * NK]; const float x3 = xb[-3 * NK];
            const float x4 = xb[-4 * NK]; const float x5 = xb[-5 * NK];
            const float x6 = xb[-6 * NK]; const float x7 = xb[-7 * NK];
            BSTEP(x0); BSTEP(x1); BSTEP(x2); BSTEP(x3);
            BSTEP(x4); BSTEP(x5); BSTEP(x6); BSTEP(x7);
            RENORM();
        }
        for (; t0 >= m + 1; --t0) { const float x = Xl[t0 * NK + jj]; BSTEP(x); }
#undef BSTEP
    }
#undef RL
#undef MATVEC
#undef RENORM

    #pragma unroll
    for (int off = 32; off > 0; off >>= 1) csum += __shfl_xor(csum, off, 64);

    if (wid == 1) {
        if (lane < NK) comb[lane] = a;
        if (lane == 0) comb[21] = csum + Orenorm;
    }
    __syncthreads();

    if (wid == 0) {
        float val = (lane < NK) ? a * comb[lane] : 0.f;
        #pragma unroll
        for (int off = 32; off > 0; off >>= 1) val += __shfl_xor(val, off, 64);
        if (lane == 0) {
            const float OF  = csum + Orenorm;
            const float num = comb[22] + comb[23];
            per_batch[b] = OF + comb[21] + __logf(val) - num;
        }
    }
}

// ---------------- final reduce: nll = sum_b (logZ_b - num_b) ----------------
__global__ __launch_bounds__(64) void reduce_kernel(
    const float* __restrict__ pb, float* __restrict__ out)
{
    float v = pb[threadIdx.x];
    #pragma unroll
    for (int off = 32; off > 0; off >>= 1) v += __shfl_xor(v, off, 64);
    if (threadIdx.x == 0) out[BSZ * SEQ * NK] = v;
}

extern "C" void kernel_launch(void* const* d_in, const int* in_sizes, int n_in,
                              void* d_out, int out_size, void* d_ws, size_t ws_size,
                              hipStream_t stream)
{
    const float* hidden  = (const float*)d_in[0];
    const float* W       = (const float*)d_in[1];
    const float* bias    = (const float*)d_in[2];
    const float* start_t = (const float*)d_in[3];
    const float* trans   = (const float*)d_in[4];
    const float* end_t   = (const float*)d_in[5];
    const int*   labels  = (const int*)d_in[6];
    const int*   mask    = (const int*)d_in[7];
    float* out = (float*)d_out;
    float* pb  = (float*)d_ws;

    gemm_bias_kernel<<<(BSZ * SEQ) / 64, 256, 0, stream>>>(hidden, W, bias, out);
    crf_kernel<<<BSZ, 128, 0, stream>>>(out, start_t, trans, end_t, labels, mask, pb);
    reduce_kernel<<<1, 64, 0, stream>>>(pb, out);
}

// Round 8
// 208.343 us; speedup vs baseline: 2.1376x; 1.0032x over previous
//
#include <hip/hip_runtime.h>

#define BSZ 64
#define SEQ 512
#define HID 768
#define NK  21

typedef short bf16x8 __attribute__((ext_vector_type(8)));
typedef float f32x4  __attribute__((ext_vector_type(4)));

__device__ __forceinline__ unsigned f2bf1(float x) {   // RNE fp32->bf16
    unsigned u = __float_as_uint(x);
    return (u + 0x7fffu + ((u >> 16) & 1u)) >> 16;
}
__device__ __forceinline__ unsigned f2bf_pk(float lo, float hi) {
    return f2bf1(lo) | (f2bf1(hi) << 16);
}

// ---------------- W pre-convert: WT[32][768] bf16, transposed, zero-padded ---
__global__ __launch_bounds__(256) void wconv_kernel(
    const float* __restrict__ W, unsigned short* __restrict__ WT)
{
    const int idx = blockIdx.x * 256 + threadIdx.x;    // 0 .. 24575
    const int n = idx / HID;
    const int k = idx - n * HID;
    unsigned short v = 0;
    if (n < NK) v = (unsigned short)f2bf1(W[(size_t)k * NK + n]);
    WT[idx] = v;
}

// ---------------- GEMM + bias: logits = hidden @ W + b (bf16 MFMA) ----------
// No LDS, no barriers. A-frags direct global->VGPR (lanes {m,m+16,m+32,m+48}
// cover 128 contiguous bytes of row m). B-frags read straight from WT in
// global (48 KB, L1/L2-resident, shared by all blocks). 8 waves/SIMD.
__global__ __launch_bounds__(256) void gemm_bias_kernel(
    const float* __restrict__ hidden, const unsigned short* __restrict__ WT,
    const float* __restrict__ bias, float* __restrict__ out)
{
    const int tid  = threadIdx.x;
    const int lane = tid & 63;
    const int wv   = tid >> 6;
    const int n    = lane & 15;                        // N (B/C/D) | M (A)
    const int quad = lane >> 4;                        // k-subchunk owner

    const int arow = blockIdx.x * 64 + wv * 16 + n;
    const float* ap = hidden + (size_t)arow * HID + quad * 8;
    const bf16x8* bp0 = (const bf16x8*)(WT + (size_t)n * HID + quad * 8);
    const bf16x8* bp1 = (const bf16x8*)(WT + (size_t)(16 + n) * HID + quad * 8);

    f32x4 acc0 = {0.f, 0.f, 0.f, 0.f};
    f32x4 acc1 = {0.f, 0.f, 0.f, 0.f};

    float4 c0a = *(const float4*)(ap + 0);
    float4 c0b = *(const float4*)(ap + 4);

    #pragma unroll
    for (int c = 0; c < HID / 32; ++c) {               // 24 K-chunks
        float4 c1a, c1b;
        if (c + 1 < HID / 32) {                        // depth-2 A prefetch
            c1a = *(const float4*)(ap + (c + 1) * 32);
            c1b = *(const float4*)(ap + (c + 1) * 32 + 4);
        }
        union { bf16x8 v; unsigned u[4]; } af;
        af.u[0] = f2bf_pk(c0a.x, c0a.y);
        af.u[1] = f2bf_pk(c0a.z, c0a.w);
        af.u[2] = f2bf_pk(c0b.x, c0b.y);
        af.u[3] = f2bf_pk(c0b.z, c0b.w);

        const bf16x8 b0 = bp0[c * 4];                  // c*32 shorts
        const bf16x8 b1 = bp1[c * 4];

        acc0 = __builtin_amdgcn_mfma_f32_16x16x32_bf16(af.v, b0, acc0, 0, 0, 0);
        acc1 = __builtin_amdgcn_mfma_f32_16x16x32_bf16(af.v, b1, acc1, 0, 0, 0);
        c0a = c1a; c0b = c1b;
    }

    // C/D layout: col = lane&15, row = quad*4 + reg
    const float b0v = bias[n];
    const float b1v = (n < NK - 16) ? bias[16 + n] : 0.f;
    const int rbase = blockIdx.x * 64 + wv * 16 + quad * 4;
    #pragma unroll
    for (int r = 0; r < 4; ++r) {
        float* op = out + (size_t)(rbase + r) * NK;
        op[n] = acc0[r] + b0v;
        if (n < NK - 16) op[16 + n] = acc1[r] + b1v;
    }
}

// ---------------- CRF: 2 waves per batch (forward + backward) ----------------
// R6 structure; alpha all-gather via ds_bpermute (VGPR results, no SALU
// hazard path) instead of v_readlane.
__global__ __launch_bounds__(128) void crf_kernel(
    const float* __restrict__ logits,
    const float* __restrict__ start_t,
    const float* __restrict__ trans,
    const float* __restrict__ end_t,
    const int* __restrict__ labels,
    const int* __restrict__ mask,
    float* __restrict__ per_batch)
{
    __shared__ __align__(16) float Xl[SEQ * NK];  // raw logits -> exp(lg - C[t])
    __shared__ float C[SEQ];                      // C[t] = lg[t][0]
    __shared__ float comb[24];                    // beta_m, OB, num parts

    const int b    = blockIdx.x;
    const int tid  = threadIdx.x;                 // 0..127
    const int lane = tid & 63;
    const int wid  = tid >> 6;                    // 0 = forward, 1 = backward

    {   // stage raw logits (coalesced float4, both waves)
        const float4* g4 = (const float4*)(logits + (size_t)b * SEQ * NK);
        float4* l4 = (float4*)Xl;
        for (int idx = tid; idx < SEQ * NK / 4; idx += 128) l4[idx] = g4[idx];
    }

    const int* lab = labels + b * SEQ;
    const int* msk = mask   + b * SEQ;

    // sequence length (mask is a prefix of ones)
    int cnt = 0;
    for (int t = lane; t < SEQ; t += 64) cnt += (msk[t] != 0);
    #pragma unroll
    for (int off = 32; off > 0; off >>= 1) cnt += __shfl_xor(cnt, off, 64);
    const int L = cnt;
    const int m = L >> 1;

    __syncthreads();

    {   // numerator partials (raw Xl)
        float numacc = 0.f;
        for (int t = tid; t < L; t += 128) {
            if (t == 0) numacc += start_t[lab[0]] + Xl[lab[0]];
            else        numacc += Xl[t * NK + lab[t]] + trans[lab[t - 1] * NK + lab[t]];
        }
        if (tid == 0) numacc += end_t[lab[L - 1]];
        #pragma unroll
        for (int off = 32; off > 0; off >>= 1) numacc += __shfl_xor(numacc, off, 64);
        if (lane == 0) comb[22 + wid] = numacc;
    }

    for (int t = tid; t < SEQ; t += 128) C[t] = Xl[t * NK];
    __syncthreads();

    for (int idx = tid; idx < SEQ * NK; idx += 128) {
        const int t = idx / NK;
        Xl[idx] = __expf(Xl[idx] - C[t]);
    }
    __syncthreads();

    const int jj = (lane < NK) ? lane : NK - 1;

#define BP(v, k) __uint_as_float(__builtin_amdgcn_ds_bpermute(4 * (k), __float_as_uint(v)))
#define MATVEC(vv, EE, outv) do {                                          \
    float s0 = BP(vv, 0) * EE[0];                                          \
    float s1 = BP(vv, 1) * EE[1];                                          \
    float s2 = BP(vv, 2) * EE[2];                                          \
    s0 = fmaf(BP(vv,  3), EE[ 3], s0); s1 = fmaf(BP(vv,  4), EE[ 4], s1);  \
    s2 = fmaf(BP(vv,  5), EE[ 5], s2); s0 = fmaf(BP(vv,  6), EE[ 6], s0);  \
    s1 = fmaf(BP(vv,  7), EE[ 7], s1); s2 = fmaf(BP(vv,  8), EE[ 8], s2);  \
    s0 = fmaf(BP(vv,  9), EE[ 9], s0); s1 = fmaf(BP(vv, 10), EE[10], s1);  \
    s2 = fmaf(BP(vv, 11), EE[11], s2); s0 = fmaf(BP(vv, 12), EE[12], s0);  \
    s1 = fmaf(BP(vv, 13), EE[13], s1); s2 = fmaf(BP(vv, 14), EE[14], s2);  \
    s0 = fmaf(BP(vv, 15), EE[15], s0); s1 = fmaf(BP(vv, 16), EE[16], s1);  \
    s2 = fmaf(BP(vv, 17), EE[17], s2); s0 = fmaf(BP(vv, 18), EE[18], s0);  \
    s1 = fmaf(BP(vv, 19), EE[19], s1); s2 = fmaf(BP(vv, 20), EE[20], s2);  \
    outv = (s0 + s1) + s2;                                                 \
} while (0)
#define RENORM() do {                                                      \
    const float mm = __uint_as_float(                                      \
        __builtin_amdgcn_readfirstlane(__float_as_uint(a)));               \
    a *= __builtin_amdgcn_rcpf(mm);                                        \
    Orenorm += __logf(mm);                                                 \
} while (0)

    float a;
    float Orenorm = 0.f;
    float csum = 0.f;

    if (wid == 0) {
        // ---------------- FORWARD: alpha_0 .. alpha_m ----------------
        float Ecol[NK];
        #pragma unroll
        for (int k = 0; k < NK; ++k) Ecol[k] = __expf(trans[k * NK + jj]);

        a = __expf(start_t[jj]) * Xl[jj];
        for (int t = lane; t <= m; t += 64) csum += C[t];

#define FSTEP(xr) do { float nv; MATVEC(a, Ecol, nv); a = nv * (xr); } while (0)
        int t0 = 1;
        for (; t0 + 7 <= m; t0 += 8) {
            const float* xb = Xl + t0 * NK + jj;
            const float x0 = xb[0];      const float x1 = xb[NK];
            const float x2 = xb[2 * NK]; const float x3 = xb[3 * NK];
            const float x4 = xb[4 * NK]; const float x5 = xb[5 * NK];
            const float x6 = xb[6 * NK]; const float x7 = xb[7 * NK];
            FSTEP(x0); FSTEP(x1); FSTEP(x2); FSTEP(x3);
            FSTEP(x4); FSTEP(x5); FSTEP(x6); FSTEP(x7);
            RENORM();
        }
        for (; t0 <= m; ++t0) { const float x = Xl[t0 * NK + jj]; FSTEP(x); }
#undef FSTEP
    } else {
        // ---------------- BACKWARD: beta_{L-1} .. beta_m ----------------
        float Erow[NK];
        #pragma unroll
        for (int k = 0; k < NK; ++k) Erow[k] = __expf(trans[jj * NK + k]);

        a = __expf(end_t[jj]);
        for (int t = m + 1 + lane; t < L; t += 64) csum += C[t];

#define BSTEP(xr) do { const float u = a * (xr); float nv; MATVEC(u, Erow, nv); a = nv; } while (0)
        int t0 = L - 1;
        for (; t0 - 7 >= m + 1; t0 -= 8) {
            const float* xb = Xl + t0 * NK + jj;
            const float x0 = xb[0];       const float x1 = xb[-NK];
            const float x2 = xb[-2 * NK]; const float x3 = xb[-3 * NK];
            const float x4 = xb[-4 * NK]; const float x5 = xb[-5 * NK];
            const float x6 = xb[-6 * NK]; const float x7 = xb[-7 * NK];
            BSTEP(x0); BSTEP(x1); BSTEP(x2); BSTEP(x3);
            BSTEP(x4); BSTEP(x5); BSTEP(x6); BSTEP(x7);
            RENORM();
        }
        for (; t0 >= m + 1; --t0) { const float x = Xl[t0 * NK + jj]; BSTEP(x); }
#undef BSTEP
    }
#undef BP
#undef MATVEC
#undef RENORM

    #pragma unroll
    for (int off = 32; off > 0; off >>= 1) csum += __shfl_xor(csum, off, 64);

    if (wid == 1) {
        if (lane < NK) comb[lane] = a;
        if (lane == 0) comb[21] = csum + Orenorm;
    }
    __syncthreads();

    if (wid == 0) {
        float val = (lane < NK) ? a * comb[lane] : 0.f;
        #pragma unroll
        for (int off = 32; off > 0; off >>= 1) val += __shfl_xor(val, off, 64);
        if (lane == 0) {
            const float OF  = csum + Orenorm;
            const float num = comb[22] + comb[23];
            per_batch[b] = OF + comb[21] + __logf(val) - num;
        }
    }
}

// ---------------- final reduce: nll = sum_b (logZ_b - num_b) ----------------
__global__ __launch_bounds__(64) void reduce_kernel(
    const float* __restrict__ pb, float* __restrict__ out)
{
    float v = pb[threadIdx.x];
    #pragma unroll
    for (int off = 32; off > 0; off >>= 1) v += __shfl_xor(v, off, 64);
    if (threadIdx.x == 0) out[BSZ * SEQ * NK] = v;
}

extern "C" void kernel_launch(void* const* d_in, const int* in_sizes, int n_in,
                              void* d_out, int out_size, void* d_ws, size_t ws_size,
                              hipStream_t stream)
{
    const float* hidden  = (const float*)d_in[0];
    const float* W       = (const float*)d_in[1];
    const float* bias    = (const float*)d_in[2];
    const float* start_t = (const float*)d_in[3];
    const float* trans   = (const float*)d_in[4];
    const float* end_t   = (const float*)d_in[5];
    const int*   labels  = (const int*)d_in[6];
    const int*   mask    = (const int*)d_in[7];
    float* out = (float*)d_out;

    float*          pb = (float*)d_ws;                         // 64 floats
    unsigned short* WT = (unsigned short*)((char*)d_ws + 256); // 32*768 bf16

    wconv_kernel<<<(32 * HID) / 256, 256, 0, stream>>>(W, WT);
    gemm_bias_kernel<<<(BSZ * SEQ) / 64, 256, 0, stream>>>(hidden, WT, bias, out);
    crf_kernel<<<BSZ, 128, 0, stream>>>(out, start_t, trans, end_t, labels, mask, pb);
    reduce_kernel<<<1, 64, 0, stream>>>(pb, out);
}